// Round 1
// baseline (457.212 us; speedup 1.0000x reference)
//
#include <hip/hip_runtime.h>
#include <hip/hip_bf16.h>
#include <math.h>

#pragma clang fp contract(off)

#define NBOX  1805
#define NB    32
#define NA    5
#define NC    80
#define HW    361
#define WDIM  19
#define NWORD 29      // ceil(1805/64)
#define SORTN 2048

typedef unsigned long long u64;
typedef unsigned int u32;

__device__ __forceinline__ float sigmoidf_(float x) {
    return 1.0f / (1.0f + expf(-x));
}

// ---------------- 1. decode ----------------
__global__ void decode_kernel(const float* __restrict__ x,
                              const float* __restrict__ anchors,
                              float4* __restrict__ rawBoxes,
                              float* __restrict__ scores,
                              int* __restrict__ labels,
                              u32* __restrict__ valid,
                              u64* __restrict__ keys) {
#pragma clang fp contract(off)
    int a = blockIdx.x;   // anchor
    int b = blockIdx.y;   // batch
    int s = threadIdx.x;  // spatial pos y*19+x
    if (s >= HW) return;
    const float* base = x + ((size_t)b * (NA * 85) + (size_t)a * 85) * HW + s;
    float tx = base[0 * HW];
    float ty = base[1 * HW];
    float tw = base[2 * HW];
    float th = base[3 * HW];
    float to = base[4 * HW];
    int xw = s % WDIM, yy = s / WDIM;
    float bx = sigmoidf_(tx) / 19.0f + (float)xw / 19.0f;
    float by = sigmoidf_(ty) / 19.0f + (float)yy / 19.0f;
    float bw = (anchors[a * 2 + 0] / 19.0f) * expf(tw);
    float bh = (anchors[a * 2 + 1] / 19.0f) * expf(th);
    float obj = sigmoidf_(to);

    float maxv = -INFINITY;
    int lab = 0;
    for (int c = 0; c < NC; ++c) {
        float v = base[(5 + c) * HW];
        if (v > maxv) { maxv = v; lab = c; }   // strict > : first max wins (matches argmax)
    }

    float x1 = bx - bw / 2.0f, y1 = by - bh / 2.0f;
    float x2 = bx + bw / 2.0f, y2 = by + bh / 2.0f;
    x1 = fminf(fmaxf(x1, 0.0f), 1.0f);
    y1 = fminf(fmaxf(y1, 0.0f), 1.0f);
    x2 = fminf(fmaxf(x2, 0.0f), 1.0f);
    y2 = fminf(fmaxf(y2, 0.0f), 1.0f);

    bool vld = obj >= 0.5f;
    int i = s * NA + a;                 // flatten order (h,w,A)
    size_t gi = (size_t)b * NBOX + i;
    rawBoxes[gi] = make_float4(x1, y1, x2, y2);
    scores[gi] = maxv;
    labels[gi] = lab;
    valid[gi] = vld ? 1u : 0u;

    // packed key: descending by sort_key, ties -> ascending index (stable argsort match)
    float sk = vld ? maxv : -1000000000.0f;
    u32 fb = __float_as_uint(sk);
    u32 asc = (fb & 0x80000000u) ? ~fb : (fb | 0x80000000u);  // monotone ascending map
    u32 dsc = ~asc;                                            // ascending sort => descending value
    keys[gi] = ((u64)dsc << 32) | (u32)i;
}

// ---------------- 2. bitonic sort + gather ----------------
__global__ __launch_bounds__(256) void sort_kernel(const u64* __restrict__ keys,
                            const float4* __restrict__ rawBoxes,
                            const float* __restrict__ scores,
                            const int* __restrict__ labels,
                            const u32* __restrict__ valid,
                            float4* __restrict__ sortedBoxes,
                            u32* __restrict__ passFlag,
                            float* __restrict__ outBoxes,
                            float* __restrict__ outScores,
                            float* __restrict__ outLabels) {
    __shared__ u64 k[SORTN];
    int b = blockIdx.x, t = threadIdx.x;
    for (int i = t; i < SORTN; i += 256)
        k[i] = (i < NBOX) ? keys[(size_t)b * NBOX + i] : ~0ULL;   // pad sorts last
    __syncthreads();
    for (int ks = 2; ks <= SORTN; ks <<= 1) {
        for (int j = ks >> 1; j > 0; j >>= 1) {
            for (int i = t; i < SORTN; i += 256) {
                int l = i ^ j;
                if (l > i) {
                    u64 a = k[i], c = k[l];
                    bool up = ((i & ks) == 0);
                    if (up ? (a > c) : (a < c)) { k[i] = c; k[l] = a; }
                }
            }
            __syncthreads();
        }
    }
    for (int s = t; s < NBOX; s += 256) {
        int idx = (int)(k[s] & 0xFFFFFFFFu);
        size_t src = (size_t)b * NBOX + idx;
        size_t dst = (size_t)b * NBOX + s;
        float4 bx = rawBoxes[src];
        float sc = scores[src];
        int lab = labels[src];
        u32 v = valid[src];
        sortedBoxes[dst] = bx;
        ((float4*)outBoxes)[dst] = bx;
        outScores[dst] = sc;
        outLabels[dst] = (float)lab;
        passFlag[dst] = (v && (sc >= 0.05f)) ? 1u : 0u;
    }
}

// ---------------- 3. suppression matrix (upper triangle, 64x64 tiles) ----------------
__global__ __launch_bounds__(64) void mask_kernel(const float4* __restrict__ sortedBoxes,
                            u64* __restrict__ masks) {
#pragma clang fp contract(off)
    int tile = blockIdx.x;
    int b = blockIdx.y;
    int ib = tile / NWORD, jb = tile % NWORD;
    if (jb < ib) return;                 // lower triangle never read by scan
    __shared__ float4 cb[64];
    int t = threadIdx.x;
    int j0 = jb * 64;
    int jj = j0 + t;
    cb[t] = (jj < NBOX) ? sortedBoxes[(size_t)b * NBOX + jj] : make_float4(0.f, 0.f, 0.f, 0.f);
    __syncthreads();
    int i = ib * 64 + t;
    if (i >= NBOX) return;
    float4 bi = sortedBoxes[(size_t)b * NBOX + i];
    float areai = (bi.z - bi.x) * (bi.w - bi.y);
    u64 bits = 0;
    for (int q = 0; q < 64; ++q) {
        int j = j0 + q;
        float4 bj = cb[q];
        float areaj = (bj.z - bj.x) * (bj.w - bj.y);
        float lt0 = fmaxf(bi.x, bj.x), lt1 = fmaxf(bi.y, bj.y);
        float rb0 = fminf(bi.z, bj.z), rb1 = fminf(bi.w, bj.w);
        float wh0 = fmaxf(rb0 - lt0, 0.0f), wh1 = fmaxf(rb1 - lt1, 0.0f);
        float inter = wh0 * wh1;
        float iou = inter / (areai + areaj - inter);   // IEEE div, no contraction
        bool sup = (iou > 0.7f) && (j > i) && (j < NBOX);
        bits |= ((u64)(sup ? 1u : 0u)) << q;
    }
    masks[((size_t)b * NBOX + i) * NWORD + jb] = bits;
}

// ---------------- 4. sequential greedy scan (1 wave / batch) ----------------
#define CH 16
__global__ __launch_bounds__(64) void scan_kernel(const u64* __restrict__ masks,
                            const u32* __restrict__ passFlag,
                            float* __restrict__ outKeep) {
    int b = blockIdx.x, lane = threadIdx.x;
    const u64* M = masks + (size_t)b * NBOX * NWORD;
    u64 own = 0;    // lane's removed-word (lane < NWORD)
    u64 diag = 0;   // all-lane copy of current diagonal word
    u64 moA[CH], mdA[CH], moB[CH], mdB[CH];

#define LOADC(MO, MD, BASE)                                              \
    _Pragma("unroll")                                                    \
    for (int q = 0; q < CH; ++q) {                                       \
        int i = (BASE) + q;                                              \
        bool ok = (i < NBOX);                                            \
        MO[q] = (ok && lane < NWORD) ? M[(size_t)i * NWORD + lane] : 0ULL; \
        MD[q] = ok ? M[(size_t)i * NWORD + (i >> 6)] : 0ULL;             \
    }

#define PROCC(MO, MD, BASE)                                              \
    _Pragma("unroll")                                                    \
    for (int q = 0; q < CH; ++q) {                                       \
        int i = (BASE) + q;                                              \
        if (i < NBOX) {                                                  \
            if ((i & 63) == 0) diag = __shfl(own, i >> 6);               \
            bool kept = (((diag >> (i & 63)) & 1ULL) == 0ULL);           \
            if (kept) {                                                  \
                if (lane >= (i >> 6) && lane < NWORD) own |= MO[q];      \
                diag |= MD[q];                                           \
            }                                                            \
        }                                                                \
    }

    LOADC(moA, mdA, 0)
    for (int base = 0; base < NBOX; base += 2 * CH) {
        LOADC(moB, mdB, base + CH)
        PROCC(moA, mdA, base)
        LOADC(moA, mdA, base + 2 * CH)
        PROCC(moB, mdB, base + CH)
    }

    __shared__ u64 rem[NWORD];
    if (lane < NWORD) rem[lane] = own;
    __syncthreads();
    for (int i = lane; i < NBOX; i += 64) {
        bool nk = (((rem[i >> 6] >> (i & 63)) & 1ULL) == 0ULL);
        float kf = (nk && passFlag[(size_t)b * NBOX + i]) ? 1.0f : 0.0f;
        outKeep[(size_t)b * NBOX + i] = kf;
    }
}

extern "C" void kernel_launch(void* const* d_in, const int* in_sizes, int n_in,
                              void* d_out, int out_size, void* d_ws, size_t ws_size,
                              hipStream_t stream) {
    const float* x = (const float*)d_in[0];
    const float* anchors = (const float*)d_in[1];
    float* out = (float*)d_out;
    float* outBoxes  = out;                       // 32*1805*4
    float* outScores = out + 231040;              // 32*1805
    float* outLabels = out + 288800;              // 32*1805
    float* outKeep   = out + 346560;              // 32*1805

    char* w = (char*)d_ws;
    float4* sortedBoxes = (float4*)(w);                   //   924160 B
    float4* rawBoxes    = (float4*)(w + 924160);          //   924160 B
    u64*    keys        = (u64*)   (w + 1848320);         //   462080 B
    float*  scores      = (float*) (w + 2310400);         //   231040 B
    int*    labels      = (int*)   (w + 2541440);         //   231040 B
    u32*    valid       = (u32*)   (w + 2772480);         //   231040 B
    u32*    passFlag    = (u32*)   (w + 3003520);         //   231040 B
    u64*    masks       = (u64*)   (w + 3234560);         // 13397120 B  (total ~16.6 MB)

    decode_kernel<<<dim3(NA, NB), 384, 0, stream>>>(x, anchors, rawBoxes, scores, labels, valid, keys);
    sort_kernel<<<NB, 256, 0, stream>>>(keys, rawBoxes, scores, labels, valid,
                                        sortedBoxes, passFlag, outBoxes, outScores, outLabels);
    mask_kernel<<<dim3(NWORD * NWORD, NB), 64, 0, stream>>>(sortedBoxes, masks);
    scan_kernel<<<NB, 64, 0, stream>>>(masks, passFlag, outKeep);
}